// Round 11
// baseline (184.289 us; speedup 1.0000x reference)
//
#include <hip/hip_runtime.h>
#include <hip/hip_bf16.h>
#include <hip/hip_cooperative_groups.h>

// CausalMixer: B=128, T=64, NA=10, NV=16, K=4, SD=512, H=256, E=32. 8192 rows.
// Round 11: SINGLE cooperative dispatch: all blocks pack weight slices ->
// grid.sync() -> R10 main body (persistent loop). Fallback: R10 2-kernel path.

namespace cg = cooperative_groups;

typedef __hip_bfloat16 bf16;
typedef unsigned short ushort_t;
typedef __attribute__((ext_vector_type(8))) short short8;
typedef __attribute__((ext_vector_type(4))) float f32x4;

#define PA_OFF 0
#define PA_TILES 56
#define PB_OFF (PA_TILES * 16 * 64 * 8 * 2)          // 917504
#define PB_TILES 36
#define FB_OFF (PB_OFF + PB_TILES * 8 * 64 * 8 * 2)  // 1212416
#define NCST 2854
#define WS_NEED (size_t)(FB_OFF + NCST * 4 + 32)

#define MFMA16(a, b, c) __builtin_amdgcn_mfma_f32_16x16x32_bf16(a, b, c, 0, 0, 0)

__device__ __forceinline__ float us2f(ushort_t x) {
  unsigned u = ((unsigned)x) << 16; float f; __builtin_memcpy(&f, &u, 4); return f;
}
__device__ __forceinline__ ushort_t f2us(float v) {
  bf16 h = __float2bfloat16(v); ushort_t r; __builtin_memcpy(&r, &h, 2); return r;
}
template <bool F32>
__device__ __forceinline__ float LD(const void* p, size_t i) {
  if (F32) return ((const float*)p)[i];
  return us2f(((const ushort_t*)p)[i]);
}

__device__ __forceinline__ int detect_f32(const void* states) {
  const unsigned short* u = (const unsigned short*)states;
  int lane = threadIdx.x & 63;
  int bad = 0;
  for (int i = lane; i < 512; i += 64) {
    unsigned short x = u[i];
    int e = (x >> 7) & 0xFF;
    if (e > 140 || (((x & 0x7FFFu) != 0) && e < 100)) bad++;
  }
  for (int off = 32; off; off >>= 1) bad += __shfl_down(bad, off);
  return __shfl(bad, 0) > 20;
}

__device__ __forceinline__ void pa_store(ushort_t* pa, int np, int k, ushort_t v) {
  int t = np >> 4, lm = np & 15, ks = k >> 5, qq = (k >> 3) & 3, j = k & 7;
  pa[(size_t)t * 8192 + ks * 512 + (qq * 16 + lm) * 8 + j] = v;
}
__device__ __forceinline__ void pb_store(ushort_t* pb, int np, int k, ushort_t v) {
  int t = np >> 4, lm = np & 15, ks = k >> 5, qq = (k >> 3) & 3, j = k & 7;
  pb[(size_t)t * 4096 + ks * 512 + (qq * 16 + lm) * 8 + j] = v;
}

struct KParams {
  char* ws;
  const void* qvals; const int* crel; const void* states; void* out;
  const void* w00l1W; const void* w00l1b; const void* w00l2W; const void* w00l2b;
  const void* b00W;  const void* b00b;
  const void* w01W;  const void* w01b;  const void* b01W;  const void* b01b;
  const void* w1l1W; const void* w1l1b; const void* w1l2W; const void* w1l2b;
  const void* b1W;   const void* b1b;
  const void* w2l1W; const void* w2l1b; const void* w2l2W; const void* w2l2b;
  const void* b2l1W; const void* b2l1b; const void* b2l2W; const void* b2l2b;
};

// ---------------- prep body (slice by gtid/T) ----------------
template <bool F32>
__device__ void prep_body(int gtid, int T, char* ws, const KParams& P) {
  ushort_t* pa = (ushort_t*)(ws + PA_OFF);
  ushort_t* pb = (ushort_t*)(ws + PB_OFF);
  float* cst = (float*)(ws + FB_OFF);
  for (int i = gtid; i < 131072; i += T) {
    int k = i >> 8, n = i & 255;
    pa_store(pa, n, k, f2us(LD<F32>(P.w1l1W, i)));
    pa_store(pa, 256 + n, k, f2us(LD<F32>(P.w2l1W, i)));
    pa_store(pa, 512 + n, k, f2us(LD<F32>(P.w00l1W, i)));
  }
  for (int i = gtid; i < 16384; i += T) {
    int k = i >> 5, n = i & 31;
    pa_store(pa, 768 + n, k, f2us(LD<F32>(P.b1W, i)));
    pa_store(pa, 800 + n, k, f2us(LD<F32>(P.b2l1W, i)));
  }
  for (int i = gtid; i < 5120; i += T) {
    int k = i / 10, n = i % 10;
    pa_store(pa, 832 + n, k, f2us(LD<F32>(P.w01W, i)));
  }
  for (int i = gtid; i < 512; i += T) {
    pa_store(pa, 842, i, f2us(LD<F32>(P.b00W, i)));
    pa_store(pa, 843, i, f2us(LD<F32>(P.b01W, i)));
  }
  for (int z = gtid; z < 2048; z += T) {
    int ks = z >> 7, qq = (z >> 5) & 3, lm = 12 + ((z >> 3) & 3), j = z & 7;
    pa[(size_t)52 * 8192 + ks * 512 + (qq * 16 + lm) * 8 + j] = 0;
  }
  for (int i = gtid; i < 139264; i += T) {
    int k = i / 544, n = i % 544;
    pb_store(pb, n, k, f2us(LD<F32>(P.w1l2W, i)));
  }
  for (int i = gtid; i < 8192; i += T) {
    int k = i >> 5, n = i & 31;
    pb_store(pb, 544 + n, k, f2us(LD<F32>(P.w2l2W, i)));
  }
  for (int i = gtid; i < NCST; i += T) {
    float x;
    if (i < 896) {
      int c = i;
      if (c < 256) x = LD<F32>(P.w1l1b, c);
      else if (c < 512) x = LD<F32>(P.w2l1b, c - 256);
      else if (c < 768) x = LD<F32>(P.w00l1b, c - 512);
      else if (c < 800) x = LD<F32>(P.b1b, c - 768);
      else if (c < 832) x = LD<F32>(P.b2l1b, c - 800);
      else if (c < 842) x = LD<F32>(P.w01b, c - 832);
      else if (c == 842) x = LD<F32>(P.b00b, 0);
      else if (c == 843) x = LD<F32>(P.b01b, 0);
      else x = 0.f;
    } else if (i < 1536) {
      int c = i - 896;
      x = (c < 544) ? LD<F32>(P.w1l2b, c) : (c < 576 ? LD<F32>(P.w2l2b, c - 544) : 0.f);
    } else if (i < 1792) {
      int j = i - 1536; float s = 0.f;
      for (int z = 0; z < 16; ++z) s += LD<F32>(P.w00l1W, (size_t)(512 + z) * 256 + j);
      x = s;
    } else if (i < 2816) x = LD<F32>(P.w00l2W, i - 1792);
    else if (i < 2820) x = LD<F32>(P.w00l2b, i - 2816);
    else if (i < 2852) x = LD<F32>(P.b2l2W, i - 2820);
    else if (i == 2852) x = LD<F32>(P.b2l2b, 0);
    else { float s = 0.f; for (int z = 0; z < 16; ++z) s += LD<F32>(P.b00W, 512 + z); x = s; }
    cst[i] = x;
  }
}

// ---------------- main body (R10, unchanged math) ----------------
struct SmemM {
  union {
    __align__(16) ushort_t sA[2][8192];
    __align__(16) ushort_t w1a[32][544];
  } u;
  __align__(16) ushort_t Am1[2][4096];
  __align__(16) ushort_t Am2[2][4096];
  __align__(16) ushort_t hb[32][264];
  float hd[256];
  float w2l[1024];
  float b1v[32][32];
  float rbv[32][32];
  float w2v[32][32];
  float w01v[32][12];
  float qv[32][10];
  unsigned char cr[32][64];
  float w0c[32][4], w0s[32][4];
  float gq[32][18];
  float gbv[32], b01v[32];
  float hid[32][33];
};

template <bool F32>
__device__ void mixer_body(SmemM& sm, const char* ws, int n0,
    const void* qvals, const int* crel, const void* states, void* out) {
  const int tid = threadIdx.x;
  const int lane = tid & 63, wv = tid >> 6;
  const int q = lane >> 4, lm = lane & 15;
  const int b_blk = n0 >> 6;
  const ushort_t* pa = (const ushort_t*)(ws + PA_OFF);
  const ushort_t* pb = (const ushort_t*)(ws + PB_OFF);
  const float* cstg = (const float*)(ws + FB_OFF);

  int sidx[7]; bool sreal[7];
#pragma unroll
  for (int i = 0; i < 7; ++i) {
    int s = wv + 8 * i;
    sreal[i] = (s < 53);
    sidx[i] = sreal[i] ? s : wv;
  }
  const ushort_t* baseA = pa + lane * 8;

  short8 curA[7];
  if (F32) {
    f32x4 va[8];
#pragma unroll
    for (int it = 0; it < 4; ++it) {
      int fi = tid + it * 512;
      int ln = fi & 63, ks = (fi >> 6) & 15, G = fi >> 10;
      int row = G * 16 + (ln & 15), col = ks * 32 + (ln >> 4) * 8;
      const f32x4* p = (const f32x4*)((const float*)states + (size_t)(n0 + row) * 512 + col);
      va[2 * it] = p[0];
      va[2 * it + 1] = p[1];
    }
#pragma unroll
    for (int i = 0; i < 7; ++i) curA[i] = *(const short8*)(baseA + (size_t)sidx[i] * 8192);
#pragma unroll
    for (int it = 0; it < 4; ++it) {
      int fi = tid + it * 512;
      int ln = fi & 63, ks = (fi >> 6) & 15, G = fi >> 10;
      f32x4 v0 = va[2 * it], v1 = va[2 * it + 1];
      ushort_t v[8];
      v[0] = f2us(v0[0]); v[1] = f2us(v0[1]); v[2] = f2us(v0[2]); v[3] = f2us(v0[3]);
      v[4] = f2us(v1[0]); v[5] = f2us(v1[1]); v[6] = f2us(v1[2]); v[7] = f2us(v1[3]);
      *(short8*)&sm.u.sA[G][(size_t)(ks * 64 + ln) * 8] = *(short8*)v;
    }
  } else {
    short8 vb[2];
#pragma unroll
    for (int it = 0; it < 2; ++it) {
      int fi = tid + it * 512;
      int ln = fi & 63, ks = (fi >> 6) & 15, G = fi >> 10;
      int row = G * 16 + (ln & 15), col = ks * 32 + (ln >> 4) * 8;
      vb[it] = *(const short8*)((const ushort_t*)states + (size_t)(n0 + row) * 512 + col);
    }
#pragma unroll
    for (int i = 0; i < 7; ++i) curA[i] = *(const short8*)(baseA + (size_t)sidx[i] * 8192);
#pragma unroll
    for (int it = 0; it < 2; ++it) {
      int fi = tid + it * 512;
      int ln = fi & 63, ks = (fi >> 6) & 15, G = fi >> 10;
      *(short8*)&sm.u.sA[G][(size_t)(ks * 64 + ln) * 8] = vb[it];
    }
  }
  for (int i = tid; i < 320; i += 512) sm.qv[i / 10][i % 10] = LD<F32>(qvals, (size_t)(n0 + i / 10) * 10 + i % 10);
  for (int i = tid; i < 2048; i += 512) sm.cr[i >> 6][i & 63] = (unsigned char)crel[(size_t)n0 * 64 + i];
  if (tid < 256) sm.hd[tid] = cstg[1536 + tid];
  for (int i = tid; i < 1024; i += 512) sm.w2l[i] = cstg[1792 + i];
  __syncthreads();

  {
    f32x4 accA[7][2];
#pragma unroll
    for (int i = 0; i < 7; ++i) { accA[i][0] = (f32x4){0,0,0,0}; accA[i][1] = (f32x4){0,0,0,0}; }
    short8 nxt[7];
#pragma unroll
    for (int ks = 0; ks < 16; ++ks) {
      if (ks < 15) {
#pragma unroll
        for (int i = 0; i < 7; ++i)
          nxt[i] = *(const short8*)(baseA + (size_t)sidx[i] * 8192 + (ks + 1) * 512);
      }
      short8 a0 = *(const short8*)&sm.u.sA[0][(ks * 64 + lane) * 8];
      short8 a1 = *(const short8*)&sm.u.sA[1][(ks * 64 + lane) * 8];
#pragma unroll
      for (int i = 0; i < 7; ++i) {
        accA[i][0] = MFMA16(a0, curA[i], accA[i][0]);
        accA[i][1] = MFMA16(a1, curA[i], accA[i][1]);
      }
#pragma unroll
      for (int i = 0; i < 7; ++i) curA[i] = nxt[i];
    }
#pragma unroll
    for (int i = 0; i < 7; ++i) {
      if (!sreal[i]) continue;
      int c = sidx[i] * 16 + lm;
      if (c >= 844) continue;
      float bias = cstg[c];
      int ks2 = (c & 255) >> 5, q2 = (c >> 3) & 3, j2 = c & 7;
#pragma unroll
      for (int G = 0; G < 2; ++G) {
        f32x4 acc = accA[i][G];
        int rb = G * 16 + q * 4;
        if (c < 256) {
#pragma unroll
          for (int g = 0; g < 4; ++g) {
            float v = acc[g] + bias;
            sm.Am1[G][(ks2 * 64 + q2 * 16 + q * 4 + g) * 8 + j2] = f2us(v > 0.f ? v : 0.f);
          }
        } else if (c < 512) {
#pragma unroll
          for (int g = 0; g < 4; ++g) {
            float v = acc[g] + bias;
            sm.Am2[G][(ks2 * 64 + q2 * 16 + q * 4 + g) * 8 + j2] = f2us(v > 0.f ? v : 0.f);
          }
        } else if (c < 768) {
#pragma unroll
          for (int g = 0; g < 4; ++g) sm.hb[rb + g][c - 512] = f2us(acc[g] + bias);
        } else if (c < 800) {
#pragma unroll
          for (int g = 0; g < 4; ++g) sm.b1v[rb + g][c - 768] = acc[g] + bias;
        } else if (c < 832) {
#pragma unroll
          for (int g = 0; g < 4; ++g) { float v = acc[g] + bias; sm.rbv[rb + g][c - 800] = v > 0.f ? v : 0.f; }
        } else if (c < 842) {
#pragma unroll
          for (int g = 0; g < 4; ++g) sm.w01v[rb + g][c - 832] = acc[g] + bias;
        } else if (c == 842) {
#pragma unroll
          for (int g = 0; g < 4; ++g) sm.gbv[rb + g] = acc[g] + bias;
        } else {
#pragma unroll
          for (int g = 0; g < 4; ++g) sm.b01v[rb + g] = acc[g] + bias;
        }
      }
    }
  }

  int tix[5]; bool treal[5];
#pragma unroll
  for (int i = 0; i < 5; ++i) {
    int t = wv + 8 * i;
    treal[i] = (t < 36);
    tix[i] = treal[i] ? t : wv;
  }
  const ushort_t* baseB = pb + lane * 8;
  short8 curB[5];
#pragma unroll
  for (int i = 0; i < 5; ++i) curB[i] = *(const short8*)(baseB + (size_t)tix[i] * 4096);
  __syncthreads();

  {
    f32x4 accB[5][2];
#pragma unroll
    for (int i = 0; i < 5; ++i) { accB[i][0] = (f32x4){0,0,0,0}; accB[i][1] = (f32x4){0,0,0,0}; }
    short8 nxt[5];
#pragma unroll
    for (int ks = 0; ks < 8; ++ks) {
      if (ks < 7) {
#pragma unroll
        for (int i = 0; i < 5; ++i)
          nxt[i] = *(const short8*)(baseB + (size_t)tix[i] * 4096 + (ks + 1) * 512);
      }
      short8 m1a0 = *(const short8*)&sm.Am1[0][(ks * 64 + lane) * 8];
      short8 m1a1 = *(const short8*)&sm.Am1[1][(ks * 64 + lane) * 8];
      short8 m2a0 = *(const short8*)&sm.Am2[0][(ks * 64 + lane) * 8];
      short8 m2a1 = *(const short8*)&sm.Am2[1][(ks * 64 + lane) * 8];
#pragma unroll
      for (int i = 0; i < 5; ++i) {
        short8 x0 = (tix[i] < 34) ? m1a0 : m2a0;
        short8 x1 = (tix[i] < 34) ? m1a1 : m2a1;
        accB[i][0] = MFMA16(x0, curB[i], accB[i][0]);
        accB[i][1] = MFMA16(x1, curB[i], accB[i][1]);
      }
#pragma unroll
      for (int i = 0; i < 5; ++i) curB[i] = nxt[i];
    }
#pragma unroll
    for (int i = 0; i < 5; ++i) {
      if (!treal[i]) continue;
      int c = tix[i] * 16 + lm;
      float bias = cstg[896 + c];
#pragma unroll
      for (int G = 0; G < 2; ++G) {
        f32x4 acc = accB[i][G];
        int rb = G * 16 + q * 4;
        if (c < 544) {
#pragma unroll
          for (int g = 0; g < 4; ++g) sm.u.w1a[rb + g][c] = f2us(fabsf(acc[g] + bias));
        } else {
          int e = c - 544;
#pragma unroll
          for (int g = 0; g < 4; ++g) sm.w2v[rb + g][e] = fabsf(acc[g] + bias);
        }
      }
    }
  }
  __syncthreads();

  if (tid < 256) {
    int r = tid >> 3, k = (tid >> 1) & 3, sflag = tid & 1;
    float a = 0.f;
    for (int j = 0; j < 256; ++j) {
      float h = us2f(sm.hb[r][j]);
      if (sflag) h += sm.hd[j];
      h = h > 0.f ? h : 0.f;
      a = fmaf(h, sm.w2l[j * 4 + k], a);
    }
    a += cstg[2816 + k];
    if (sflag) sm.w0s[r][k] = a; else sm.w0c[r][k] = a;
  }
  __syncthreads();

  {
    int r = tid >> 4, v = tid & 15;
    bool sp = (v == b_blk);
    const float* w0 = sp ? sm.w0s[r] : sm.w0c[r];
    float g = sm.gbv[r] + (sp ? cstg[2853] : 0.f);
#pragma unroll
    for (int k = 0; k < 4; ++k) {
      int a = sm.cr[r][k * 16 + v];
      g = fmaf(sm.qv[r][a], fabsf(w0[k]), g);
    }
    sm.gq[r][v] = g;
  }
  if (tid < 32) {
    float o = sm.b01v[tid];
#pragma unroll
    for (int a = 0; a < 10; ++a) o = fmaf(sm.qv[tid][a], sm.w01v[tid][a], o);
    sm.gq[tid][16] = o;
  }
  __syncthreads();

  for (int p = tid; p < 1024; p += 512) {
    int r = p >> 5, e = p & 31;
    float h = sm.b1v[r][e];
#pragma unroll
    for (int v = 0; v < 17; ++v) h = fmaf(sm.gq[r][v], us2f(sm.u.w1a[r][v * 32 + e]), h);
    float hid = h > 0.f ? h : (expf(h) - 1.f);
    sm.hid[r][e] = hid * sm.w2v[r][e] + sm.rbv[r][e] * cstg[2820 + e];
  }
  __syncthreads();

  if (tid < 32) {
    float y = cstg[2852];
#pragma unroll
    for (int e = 0; e < 32; ++e) y += sm.hid[tid][e];
    if (F32) ((float*)out)[n0 + tid] = y;
    else ((bf16*)out)[n0 + tid] = __float2bfloat16(y);
  }
  __syncthreads();   // protect smem reuse in persistent loop
}

// ---------------- cooperative fused kernel ----------------
__global__ __launch_bounds__(512, 2) void causal_mixer_coop(KParams P) {
  __shared__ SmemM sm;
  int gtid = blockIdx.x * 512 + threadIdx.x;
  int T = gridDim.x * 512;
  int isf32 = detect_f32(P.states);
  if (isf32) prep_body<true>(gtid, T, P.ws, P);
  else       prep_body<false>(gtid, T, P.ws, P);
  cg::this_grid().sync();
  for (int blk = blockIdx.x; blk < 256; blk += gridDim.x) {
    int n0 = blk * 32;
    if (isf32) mixer_body<true>(sm, P.ws, n0, P.qvals, P.crel, P.states, P.out);
    else       mixer_body<false>(sm, P.ws, n0, P.qvals, P.crel, P.states, P.out);
  }
}

// ---------------- fallback: R10 two-kernel path ----------------
__global__ __launch_bounds__(256) void prep_kernel(KParams P) {
  int gtid = blockIdx.x * 256 + threadIdx.x;
  int T = gridDim.x * 256;
  if (detect_f32(P.states)) prep_body<true>(gtid, T, P.ws, P);
  else                      prep_body<false>(gtid, T, P.ws, P);
}

__global__ __launch_bounds__(512, 2) void causal_mixer_mfma(KParams P) {
  __shared__ SmemM sm;
  int n0 = blockIdx.x * 32;
  if (detect_f32(P.states))
    mixer_body<true>(sm, P.ws, n0, P.qvals, P.crel, P.states, P.out);
  else
    mixer_body<false>(sm, P.ws, n0, P.qvals, P.crel, P.states, P.out);
}

extern "C" void kernel_launch(void* const* d_in, const int* in_sizes, int n_in,
                              void* d_out, int out_size, void* d_ws, size_t ws_size,
                              hipStream_t stream) {
  KParams P;
  P.ws = (char*)d_ws;
  P.qvals = d_in[0]; P.crel = (const int*)d_in[1]; P.states = d_in[2]; P.out = d_out;
  P.w00l1W = d_in[3];  P.w00l1b = d_in[4];  P.w00l2W = d_in[5];  P.w00l2b = d_in[6];
  P.b00W   = d_in[7];  P.b00b   = d_in[8];
  P.w01W   = d_in[9];  P.w01b   = d_in[10]; P.b01W   = d_in[11]; P.b01b   = d_in[12];
  P.w1l1W  = d_in[13]; P.w1l1b  = d_in[14]; P.w1l2W  = d_in[15]; P.w1l2b  = d_in[16];
  P.b1W    = d_in[17]; P.b1b    = d_in[18];
  P.w2l1W  = d_in[19]; P.w2l1b  = d_in[20]; P.w2l2W  = d_in[21]; P.w2l2b  = d_in[22];
  P.b2l1W  = d_in[23]; P.b2l1b  = d_in[24]; P.b2l2W  = d_in[25]; P.b2l2b  = d_in[26];

  bool launched = false;
  if (ws_size >= WS_NEED) {
    int occ = 0;
    hipError_t e = hipOccupancyMaxActiveBlocksPerMultiprocessor(
        &occ, (const void*)causal_mixer_coop, 512, 0);
    int nCU = 256;
    hipDeviceProp_t prop;
    if (hipGetDeviceProperties(&prop, 0) == hipSuccess) nCU = prop.multiProcessorCount;
    if (e == hipSuccess && occ > 0) {
      int grid = occ * nCU;
      if (grid > 256) grid = 256;
      void* args[] = { &P };
      hipError_t le = hipLaunchCooperativeKernel(
          (const void*)causal_mixer_coop, dim3(grid), dim3(512), args, 0, stream);
      if (le == hipSuccess) launched = true;
    }
    if (!launched) {
      hipLaunchKernelGGL(prep_kernel, dim3(256), dim3(256), 0, stream, P);
      hipLaunchKernelGGL(causal_mixer_mfma, dim3(256), dim3(512), 0, stream, P);
      launched = true;
    }
  }
  if (!launched) {
    // ws too small: two-kernel path still needs ws; as a last resort run
    // the cooperative kernel with whatever ws there is (requires WS_NEED).
    // Practically ws_size has always been >= WS_NEED in this harness.
    hipLaunchKernelGGL(prep_kernel, dim3(256), dim3(256), 0, stream, P);
    hipLaunchKernelGGL(causal_mixer_mfma, dim3(256), dim3(512), 0, stream, P);
  }
}

// Round 12
// 146.658 us; speedup vs baseline: 1.2566x; 1.2566x over previous
//
#include <hip/hip_runtime.h>
#include <hip/hip_bf16.h>

// CausalMixer: B=128, T=64, NA=10, NV=16, K=4, SD=512, H=256, E=32. 8192 rows.
// Round 12: R10 two-kernel path + C1 folded into phase B as MFMA tiles 36/37
// (w00l2 packed into PB; relu(hb)/relu(hb+hd) stored lane-order as A-operands).

typedef __hip_bfloat16 bf16;
typedef unsigned short ushort_t;
typedef __attribute__((ext_vector_type(8))) short short8;
typedef __attribute__((ext_vector_type(4))) float f32x4;

#define PA_OFF 0
#define PA_TILES 56                                  // N=896 padded (844 real)
#define PB_OFF (PA_TILES * 16 * 64 * 8 * 2)          // 917504
#define PB_TILES 38                                  // 0..33 w1l2, 34..35 w2l2, 36/37 w00l2
#define FB_OFF (PB_OFF + PB_TILES * 8 * 64 * 8 * 2)  // 1228800
#define NCST 2854
#define WS_NEED (size_t)(FB_OFF + NCST * 4 + 32)

#define MFMA16(a, b, c) __builtin_amdgcn_mfma_f32_16x16x32_bf16(a, b, c, 0, 0, 0)

__device__ __forceinline__ float us2f(ushort_t x) {
  unsigned u = ((unsigned)x) << 16; float f; __builtin_memcpy(&f, &u, 4); return f;
}
__device__ __forceinline__ ushort_t f2us(float v) {
  bf16 h = __float2bfloat16(v); ushort_t r; __builtin_memcpy(&r, &h, 2); return r;
}
template <bool F32>
__device__ __forceinline__ float LD(const void* p, size_t i) {
  if (F32) return ((const float*)p)[i];
  return us2f(((const ushort_t*)p)[i]);
}

// wave-level dtype probe: 1 = float32, 0 = bf16
__device__ __forceinline__ int detect_f32(const void* states) {
  const unsigned short* u = (const unsigned short*)states;
  int lane = threadIdx.x & 63;
  int bad = 0;
  for (int i = lane; i < 512; i += 64) {
    unsigned short x = u[i];
    int e = (x >> 7) & 0xFF;
    if (e > 140 || (((x & 0x7FFFu) != 0) && e < 100)) bad++;
  }
  for (int off = 32; off; off >>= 1) bad += __shfl_down(bad, off);
  return __shfl(bad, 0) > 20;
}

// packed-layout stores: element (n', k) -> MFMA lane order
__device__ __forceinline__ void pa_store(ushort_t* pa, int np, int k, ushort_t v) {
  int t = np >> 4, lm = np & 15, ks = k >> 5, qq = (k >> 3) & 3, j = k & 7;
  pa[(size_t)t * 8192 + ks * 512 + (qq * 16 + lm) * 8 + j] = v;
}
__device__ __forceinline__ void pb_store(ushort_t* pb, int np, int k, ushort_t v) {
  int t = np >> 4, lm = np & 15, ks = k >> 5, qq = (k >> 3) & 3, j = k & 7;
  pb[(size_t)t * 4096 + ks * 512 + (qq * 16 + lm) * 8 + j] = v;
}

// ---------------- prep ----------------
template <bool F32>
__device__ void prep_body(int gtid, int T, char* ws,
    const void* w00l1W, const void* w00l1b, const void* w00l2W, const void* w00l2b,
    const void* b00W, const void* b00b,
    const void* w01W, const void* w01b, const void* b01W, const void* b01b,
    const void* w1l1W, const void* w1l1b, const void* w1l2W, const void* w1l2b,
    const void* b1W, const void* b1b,
    const void* w2l1W, const void* w2l1b, const void* w2l2W, const void* w2l2b,
    const void* b2l1W, const void* b2l1b, const void* b2l2W, const void* b2l2b) {
  ushort_t* pa = (ushort_t*)(ws + PA_OFF);
  ushort_t* pb = (ushort_t*)(ws + PB_OFF);
  float* cst = (float*)(ws + FB_OFF);
  for (int i = gtid; i < 131072; i += T) {
    int k = i >> 8, n = i & 255;
    pa_store(pa, n, k, f2us(LD<F32>(w1l1W, i)));
    pa_store(pa, 256 + n, k, f2us(LD<F32>(w2l1W, i)));
    pa_store(pa, 512 + n, k, f2us(LD<F32>(w00l1W, i)));
  }
  for (int i = gtid; i < 16384; i += T) {
    int k = i >> 5, n = i & 31;
    pa_store(pa, 768 + n, k, f2us(LD<F32>(b1W, i)));
    pa_store(pa, 800 + n, k, f2us(LD<F32>(b2l1W, i)));
  }
  for (int i = gtid; i < 5120; i += T) {
    int k = i / 10, n = i % 10;
    pa_store(pa, 832 + n, k, f2us(LD<F32>(w01W, i)));
  }
  for (int i = gtid; i < 512; i += T) {
    pa_store(pa, 842, i, f2us(LD<F32>(b00W, i)));
    pa_store(pa, 843, i, f2us(LD<F32>(b01W, i)));
  }
  for (int z = gtid; z < 2048; z += T) {
    int ks = z >> 7, qq = (z >> 5) & 3, lm = 12 + ((z >> 3) & 3), j = z & 7;
    pa[(size_t)52 * 8192 + ks * 512 + (qq * 16 + lm) * 8 + j] = 0;
  }
  for (int i = gtid; i < 139264; i += T) {
    int k = i / 544, n = i % 544;
    pb_store(pb, n, k, f2us(LD<F32>(w1l2W, i)));
  }
  for (int i = gtid; i < 8192; i += T) {
    int k = i >> 5, n = i & 31;
    pb_store(pb, 544 + n, k, f2us(LD<F32>(w2l2W, i)));
  }
  // PB tiles 36/37: w00l2 (256x4) in cols 0..3, zeros elsewhere. One pass, no race.
  for (int i = gtid; i < 8192; i += T) {
    int k = i & 255, lm = (i >> 8) & 15, tt = 36 + (i >> 12);
    ushort_t v = (lm < 4) ? f2us(LD<F32>(w00l2W, k * 4 + lm)) : (ushort_t)0;
    pb_store(pb, tt * 16 + lm, k, v);
  }
  // consts: biasA[0,896) biasB[896,1536) hd[1536,1792) w00l2W[1792,2816)
  //         w00l2b[2816,2820) b2l2W[2820,2852) b2l2b[2852] gd[2853]
  for (int i = gtid; i < NCST; i += T) {
    float x;
    if (i < 896) {
      int c = i;
      if (c < 256) x = LD<F32>(w1l1b, c);
      else if (c < 512) x = LD<F32>(w2l1b, c - 256);
      else if (c < 768) x = LD<F32>(w00l1b, c - 512);
      else if (c < 800) x = LD<F32>(b1b, c - 768);
      else if (c < 832) x = LD<F32>(b2l1b, c - 800);
      else if (c < 842) x = LD<F32>(w01b, c - 832);
      else if (c == 842) x = LD<F32>(b00b, 0);
      else if (c == 843) x = LD<F32>(b01b, 0);
      else x = 0.f;
    } else if (i < 1536) {
      int c = i - 896;
      x = (c < 544) ? LD<F32>(w1l2b, c) : (c < 576 ? LD<F32>(w2l2b, c - 544) : 0.f);
    } else if (i < 1792) {
      int j = i - 1536; float s = 0.f;
      for (int z = 0; z < 16; ++z) s += LD<F32>(w00l1W, (size_t)(512 + z) * 256 + j);
      x = s;
    } else if (i < 2816) x = LD<F32>(w00l2W, i - 1792);
    else if (i < 2820) x = LD<F32>(w00l2b, i - 2816);
    else if (i < 2852) x = LD<F32>(b2l2W, i - 2820);
    else if (i == 2852) x = LD<F32>(b2l2b, 0);
    else { float s = 0.f; for (int z = 0; z < 16; ++z) s += LD<F32>(b00W, 512 + z); x = s; }
    cst[i] = x;
  }
}

__global__ __launch_bounds__(256) void prep_kernel(char* ws, const void* states,
    const void* w00l1W, const void* w00l1b, const void* w00l2W, const void* w00l2b,
    const void* b00W, const void* b00b,
    const void* w01W, const void* w01b, const void* b01W, const void* b01b,
    const void* w1l1W, const void* w1l1b, const void* w1l2W, const void* w1l2b,
    const void* b1W, const void* b1b,
    const void* w2l1W, const void* w2l1b, const void* w2l2W, const void* w2l2b,
    const void* b2l1W, const void* b2l1b, const void* b2l2W, const void* b2l2b) {
  int gtid = blockIdx.x * 256 + threadIdx.x;
  int T = gridDim.x * 256;
  if (detect_f32(states))
    prep_body<true>(gtid, T, ws, w00l1W, w00l1b, w00l2W, w00l2b, b00W, b00b,
        w01W, w01b, b01W, b01b, w1l1W, w1l1b, w1l2W, w1l2b, b1W, b1b,
        w2l1W, w2l1b, w2l2W, w2l2b, b2l1W, b2l1b, b2l2W, b2l2b);
  else
    prep_body<false>(gtid, T, ws, w00l1W, w00l1b, w00l2W, w00l2b, b00W, b00b,
        w01W, w01b, b01W, b01b, w1l1W, w1l1b, w1l2W, w1l2b, b1W, b1b,
        w2l1W, w2l1b, w2l2W, w2l2b, b2l1W, b2l1b, b2l2W, b2l2b);
}

// ---------------- main MFMA kernel: 32 rows/block, 8 waves ----------------
struct SmemM {
  union {
    __align__(16) ushort_t sA[2][8192];   // states, lane order (phase A only)
    __align__(16) ushort_t w1a[32][544];  // |w1 raw| bf16 (phase B output)
  } u;
  __align__(16) ushort_t Am1[2][4096];    // relu(s@w1l1+b), lane order
  __align__(16) ushort_t Am2[2][4096];    // relu(s@w2l1+b), lane order
  __align__(16) ushort_t hbC[2][4096];    // relu(s@w00l1+b), lane order
  __align__(16) ushort_t hbS[2][4096];    // relu(s@w00l1+b+hd), lane order
  float hd[256];
  float b1v[32][32];
  float rbv[32][32];
  float w2v[32][32];
  float w01v[32][12];
  float qv[32][10];
  unsigned char cr[32][64];
  float w0c[32][4], w0s[32][4];
  float gq[32][18];
  float gbv[32], b01v[32];
  float hid[32][33];
};

template <bool F32>
__device__ void mixer_body(SmemM& sm, const char* ws, int n0,
    const void* qvals, const int* crel, const void* states, void* out) {
  const int tid = threadIdx.x;                // 0..511
  const int lane = tid & 63, wv = tid >> 6;   // 8 waves
  const int q = lane >> 4, lm = lane & 15;
  const int b_blk = n0 >> 6;
  const ushort_t* pa = (const ushort_t*)(ws + PA_OFF);
  const ushort_t* pb = (const ushort_t*)(ws + PB_OFF);
  const float* cstg = (const float*)(ws + FB_OFF);

  int sidx[7]; bool sreal[7];
#pragma unroll
  for (int i = 0; i < 7; ++i) {
    int s = wv + 8 * i;
    sreal[i] = (s < 53);
    sidx[i] = sreal[i] ? s : wv;
  }
  const ushort_t* baseA = pa + lane * 8;

  // ---- stage: batched deep loads, early A-phase B-tile loads ----
  short8 curA[7];
  if (F32) {
    f32x4 va[8];
#pragma unroll
    for (int it = 0; it < 4; ++it) {
      int fi = tid + it * 512;
      int ln = fi & 63, ks = (fi >> 6) & 15, G = fi >> 10;
      int row = G * 16 + (ln & 15), col = ks * 32 + (ln >> 4) * 8;
      const f32x4* p = (const f32x4*)((const float*)states + (size_t)(n0 + row) * 512 + col);
      va[2 * it] = p[0];
      va[2 * it + 1] = p[1];
    }
#pragma unroll
    for (int i = 0; i < 7; ++i) curA[i] = *(const short8*)(baseA + (size_t)sidx[i] * 8192);
#pragma unroll
    for (int it = 0; it < 4; ++it) {
      int fi = tid + it * 512;
      int ln = fi & 63, ks = (fi >> 6) & 15, G = fi >> 10;
      f32x4 v0 = va[2 * it], v1 = va[2 * it + 1];
      ushort_t v[8];
      v[0] = f2us(v0[0]); v[1] = f2us(v0[1]); v[2] = f2us(v0[2]); v[3] = f2us(v0[3]);
      v[4] = f2us(v1[0]); v[5] = f2us(v1[1]); v[6] = f2us(v1[2]); v[7] = f2us(v1[3]);
      *(short8*)&sm.u.sA[G][(size_t)(ks * 64 + ln) * 8] = *(short8*)v;
    }
  } else {
    short8 vb[2];
#pragma unroll
    for (int it = 0; it < 2; ++it) {
      int fi = tid + it * 512;
      int ln = fi & 63, ks = (fi >> 6) & 15, G = fi >> 10;
      int row = G * 16 + (ln & 15), col = ks * 32 + (ln >> 4) * 8;
      vb[it] = *(const short8*)((const ushort_t*)states + (size_t)(n0 + row) * 512 + col);
    }
#pragma unroll
    for (int i = 0; i < 7; ++i) curA[i] = *(const short8*)(baseA + (size_t)sidx[i] * 8192);
#pragma unroll
    for (int it = 0; it < 2; ++it) {
      int fi = tid + it * 512;
      int ln = fi & 63, ks = (fi >> 6) & 15, G = fi >> 10;
      *(short8*)&sm.u.sA[G][(size_t)(ks * 64 + ln) * 8] = vb[it];
    }
  }
  for (int i = tid; i < 320; i += 512) sm.qv[i / 10][i % 10] = LD<F32>(qvals, (size_t)(n0 + i / 10) * 10 + i % 10);
  for (int i = tid; i < 2048; i += 512) sm.cr[i >> 6][i & 63] = (unsigned char)crel[(size_t)n0 * 64 + i];
  if (tid < 256) sm.hd[tid] = cstg[1536 + tid];
  __syncthreads();

  // ---- Phase A: ks-outer, 7 strips/wave, acc live across K ----
  {
    f32x4 accA[7][2];
#pragma unroll
    for (int i = 0; i < 7; ++i) { accA[i][0] = (f32x4){0,0,0,0}; accA[i][1] = (f32x4){0,0,0,0}; }
    short8 nxt[7];
#pragma unroll
    for (int ks = 0; ks < 16; ++ks) {
      if (ks < 15) {
#pragma unroll
        for (int i = 0; i < 7; ++i)
          nxt[i] = *(const short8*)(baseA + (size_t)sidx[i] * 8192 + (ks + 1) * 512);
      }
      short8 a0 = *(const short8*)&sm.u.sA[0][(ks * 64 + lane) * 8];
      short8 a1 = *(const short8*)&sm.u.sA[1][(ks * 64 + lane) * 8];
#pragma unroll
      for (int i = 0; i < 7; ++i) {
        accA[i][0] = MFMA16(a0, curA[i], accA[i][0]);
        accA[i][1] = MFMA16(a1, curA[i], accA[i][1]);
      }
#pragma unroll
      for (int i = 0; i < 7; ++i) curA[i] = nxt[i];
    }
    // writeback
#pragma unroll
    for (int i = 0; i < 7; ++i) {
      if (!sreal[i]) continue;
      int c = sidx[i] * 16 + lm;
      if (c >= 844) continue;
      float bias = cstg[c];
      int ks2 = (c & 255) >> 5, q2 = (c >> 3) & 3, j2 = c & 7;
      int li = (ks2 * 64 + q2 * 16 + q * 4) * 8 + j2;
#pragma unroll
      for (int G = 0; G < 2; ++G) {
        f32x4 acc = accA[i][G];
        int rb = G * 16 + q * 4;
        if (c < 256) {
#pragma unroll
          for (int g = 0; g < 4; ++g) {
            float v = acc[g] + bias;
            sm.Am1[G][li + g * 8] = f2us(v > 0.f ? v : 0.f);
          }
        } else if (c < 512) {
#pragma unroll
          for (int g = 0; g < 4; ++g) {
            float v = acc[g] + bias;
            sm.Am2[G][li + g * 8] = f2us(v > 0.f ? v : 0.f);
          }
        } else if (c < 768) {
          float hdv = sm.hd[c - 512];
#pragma unroll
          for (int g = 0; g < 4; ++g) {
            float v = acc[g] + bias;
            sm.hbC[G][li + g * 8] = f2us(v > 0.f ? v : 0.f);
            float vs = v + hdv;
            sm.hbS[G][li + g * 8] = f2us(vs > 0.f ? vs : 0.f);
          }
        } else if (c < 800) {
#pragma unroll
          for (int g = 0; g < 4; ++g) sm.b1v[rb + g][c - 768] = acc[g] + bias;
        } else if (c < 832) {
#pragma unroll
          for (int g = 0; g < 4; ++g) { float v = acc[g] + bias; sm.rbv[rb + g][c - 800] = v > 0.f ? v : 0.f; }
        } else if (c < 842) {
#pragma unroll
          for (int g = 0; g < 4; ++g) sm.w01v[rb + g][c - 832] = acc[g] + bias;
        } else if (c == 842) {
#pragma unroll
          for (int g = 0; g < 4; ++g) sm.gbv[rb + g] = acc[g] + bias;
        } else {
#pragma unroll
          for (int g = 0; g < 4; ++g) sm.b01v[rb + g] = acc[g] + bias;
        }
      }
    }
  }

  // phase-B strips + early B-tile loads (before the barrier)
  int tix[5]; bool treal[5];
#pragma unroll
  for (int i = 0; i < 5; ++i) {
    int t = wv + 8 * i;
    treal[i] = (t < 38);
    tix[i] = treal[i] ? t : wv;
  }
  const ushort_t* baseB = pb + lane * 8;
  short8 curB[5];
#pragma unroll
  for (int i = 0; i < 5; ++i) curB[i] = *(const short8*)(baseB + (size_t)tix[i] * 4096);
  __syncthreads();

  // ---- Phase B: 38 tiles. A per strip: Am1 / Am2 / hbC / hbS ----
  {
    const ushort_t* As0[5]; const ushort_t* As1[5];
#pragma unroll
    for (int i = 0; i < 5; ++i) {
      int t = tix[i];
      As0[i] = (t < 34) ? sm.Am1[0] : (t < 36 ? sm.Am2[0] : (t == 36 ? sm.hbC[0] : sm.hbS[0]));
      As1[i] = (t < 34) ? sm.Am1[1] : (t < 36 ? sm.Am2[1] : (t == 36 ? sm.hbC[1] : sm.hbS[1]));
    }
    f32x4 accB[5][2];
#pragma unroll
    for (int i = 0; i < 5; ++i) { accB[i][0] = (f32x4){0,0,0,0}; accB[i][1] = (f32x4){0,0,0,0}; }
    short8 nxt[5];
#pragma unroll
    for (int ks = 0; ks < 8; ++ks) {
      if (ks < 7) {
#pragma unroll
        for (int i = 0; i < 5; ++i)
          nxt[i] = *(const short8*)(baseB + (size_t)tix[i] * 4096 + (ks + 1) * 512);
      }
      int ao = (ks * 64 + lane) * 8;
#pragma unroll
      for (int i = 0; i < 5; ++i) {
        short8 x0 = *(const short8*)(As0[i] + ao);
        short8 x1 = *(const short8*)(As1[i] + ao);
        accB[i][0] = MFMA16(x0, curB[i], accB[i][0]);
        accB[i][1] = MFMA16(x1, curB[i], accB[i][1]);
      }
#pragma unroll
      for (int i = 0; i < 5; ++i) curB[i] = nxt[i];
    }
#pragma unroll
    for (int i = 0; i < 5; ++i) {
      if (!treal[i]) continue;
      int t = tix[i];
      int c = t * 16 + lm;
#pragma unroll
      for (int G = 0; G < 2; ++G) {
        f32x4 acc = accB[i][G];
        int rb = G * 16 + q * 4;
        if (t < 34) {
          float bias = cstg[896 + c];
#pragma unroll
          for (int g = 0; g < 4; ++g) sm.u.w1a[rb + g][c] = f2us(fabsf(acc[g] + bias));
        } else if (t < 36) {
          float bias = cstg[896 + c];
          int e = c - 544;
#pragma unroll
          for (int g = 0; g < 4; ++g) sm.w2v[rb + g][e] = fabsf(acc[g] + bias);
        } else if (t == 36) {
          if (lm < 4) {
            float bias = cstg[2816 + lm];
#pragma unroll
            for (int g = 0; g < 4; ++g) sm.w0c[rb + g][lm] = acc[g] + bias;
          }
        } else {
          if (lm < 4) {
            float bias = cstg[2816 + lm];
#pragma unroll
            for (int g = 0; g < 4; ++g) sm.w0s[rb + g][lm] = acc[g] + bias;
          }
        }
      }
    }
  }
  __syncthreads();

  // ---- C2: gq ----
  {
    int r = tid >> 4, v = tid & 15;
    bool sp = (v == b_blk);
    const float* w0 = sp ? sm.w0s[r] : sm.w0c[r];
    float g = sm.gbv[r] + (sp ? cstg[2853] : 0.f);
#pragma unroll
    for (int k = 0; k < 4; ++k) {
      int a = sm.cr[r][k * 16 + v];
      g = fmaf(sm.qv[r][a], fabsf(w0[k]), g);
    }
    sm.gq[r][v] = g;
  }
  if (tid < 32) {
    float o = sm.b01v[tid];
#pragma unroll
    for (int a = 0; a < 10; ++a) o = fmaf(sm.qv[tid][a], sm.w01v[tid][a], o);
    sm.gq[tid][16] = o;
  }
  __syncthreads();

  // ---- C3: hidden = elu(sum_v gq*|w1| + b1); fuse *w2 + rb*b2l2W ----
  for (int p = tid; p < 1024; p += 512) {
    int r = p >> 5, e = p & 31;
    float h = sm.b1v[r][e];
#pragma unroll
    for (int v = 0; v < 17; ++v) h = fmaf(sm.gq[r][v], us2f(sm.u.w1a[r][v * 32 + e]), h);
    float hid = h > 0.f ? h : (expf(h) - 1.f);
    sm.hid[r][e] = hid * sm.w2v[r][e] + sm.rbv[r][e] * cstg[2820 + e];
  }
  __syncthreads();

  // ---- C4: reduce + store ----
  if (tid < 32) {
    float y = cstg[2852];
#pragma unroll
    for (int e = 0; e < 32; ++e) y += sm.hid[tid][e];
    if (F32) ((float*)out)[n0 + tid] = y;
    else ((bf16*)out)[n0 + tid] = __float2bfloat16(y);
  }
}

__global__ __launch_bounds__(512, 2) void causal_mixer_mfma(const char* ws,
    const void* qvals, const int* crel, const void* states, void* out) {
  __shared__ SmemM sm;
  int n0 = blockIdx.x * 32;
  if (detect_f32(states))
    mixer_body<true>(sm, ws, n0, qvals, crel, states, out);
  else
    mixer_body<false>(sm, ws, n0, qvals, crel, states, out);
}

extern "C" void kernel_launch(void* const* d_in, const int* in_sizes, int n_in,
                              void* d_out, int out_size, void* d_ws, size_t ws_size,
                              hipStream_t stream) {
  char* ws = (char*)d_ws;
  hipLaunchKernelGGL(prep_kernel, dim3(512), dim3(256), 0, stream, ws, d_in[2],
      d_in[3], d_in[4], d_in[5], d_in[6], d_in[7], d_in[8],
      d_in[9], d_in[10], d_in[11], d_in[12],
      d_in[13], d_in[14], d_in[15], d_in[16], d_in[17], d_in[18],
      d_in[19], d_in[20], d_in[21], d_in[22], d_in[23], d_in[24],
      d_in[25], d_in[26]);
  hipLaunchKernelGGL(causal_mixer_mfma, dim3(256), dim3(512), 0, stream, ws,
      d_in[0], (const int*)d_in[1], d_in[2], d_out);
}

// Round 13
// 144.410 us; speedup vs baseline: 1.2762x; 1.0156x over previous
//
#include <hip/hip_runtime.h>
#include <hip/hip_bf16.h>

// CausalMixer: B=128, T=64, NA=10, NV=16, K=4, SD=512, H=256, E=32. 8192 rows.
// Round 13: R12 + depth-3 B-operand prefetch ring (bA[3][7] / bB[3][5]) so
// each ks-iteration waits only on loads issued 3 iterations earlier
// (partial vmcnt instead of wait-all -> ~3x L2 latency cover).

typedef __hip_bfloat16 bf16;
typedef unsigned short ushort_t;
typedef __attribute__((ext_vector_type(8))) short short8;
typedef __attribute__((ext_vector_type(4))) float f32x4;

#define PA_OFF 0
#define PA_TILES 56                                  // N=896 padded (844 real)
#define PB_OFF (PA_TILES * 16 * 64 * 8 * 2)          // 917504
#define PB_TILES 38                                  // 0..33 w1l2, 34..35 w2l2, 36/37 w00l2
#define FB_OFF (PB_OFF + PB_TILES * 8 * 64 * 8 * 2)  // 1228800
#define NCST 2854
#define WS_NEED (size_t)(FB_OFF + NCST * 4 + 32)

#define MFMA16(a, b, c) __builtin_amdgcn_mfma_f32_16x16x32_bf16(a, b, c, 0, 0, 0)

__device__ __forceinline__ float us2f(ushort_t x) {
  unsigned u = ((unsigned)x) << 16; float f; __builtin_memcpy(&f, &u, 4); return f;
}
__device__ __forceinline__ ushort_t f2us(float v) {
  bf16 h = __float2bfloat16(v); ushort_t r; __builtin_memcpy(&r, &h, 2); return r;
}
template <bool F32>
__device__ __forceinline__ float LD(const void* p, size_t i) {
  if (F32) return ((const float*)p)[i];
  return us2f(((const ushort_t*)p)[i]);
}

// wave-level dtype probe: 1 = float32, 0 = bf16
__device__ __forceinline__ int detect_f32(const void* states) {
  const unsigned short* u = (const unsigned short*)states;
  int lane = threadIdx.x & 63;
  int bad = 0;
  for (int i = lane; i < 512; i += 64) {
    unsigned short x = u[i];
    int e = (x >> 7) & 0xFF;
    if (e > 140 || (((x & 0x7FFFu) != 0) && e < 100)) bad++;
  }
  for (int off = 32; off; off >>= 1) bad += __shfl_down(bad, off);
  return __shfl(bad, 0) > 20;
}

// packed-layout stores: element (n', k) -> MFMA lane order
__device__ __forceinline__ void pa_store(ushort_t* pa, int np, int k, ushort_t v) {
  int t = np >> 4, lm = np & 15, ks = k >> 5, qq = (k >> 3) & 3, j = k & 7;
  pa[(size_t)t * 8192 + ks * 512 + (qq * 16 + lm) * 8 + j] = v;
}
__device__ __forceinline__ void pb_store(ushort_t* pb, int np, int k, ushort_t v) {
  int t = np >> 4, lm = np & 15, ks = k >> 5, qq = (k >> 3) & 3, j = k & 7;
  pb[(size_t)t * 4096 + ks * 512 + (qq * 16 + lm) * 8 + j] = v;
}

// ---------------- prep ----------------
template <bool F32>
__device__ void prep_body(int gtid, int T, char* ws,
    const void* w00l1W, const void* w00l1b, const void* w00l2W, const void* w00l2b,
    const void* b00W, const void* b00b,
    const void* w01W, const void* w01b, const void* b01W, const void* b01b,
    const void* w1l1W, const void* w1l1b, const void* w1l2W, const void* w1l2b,
    const void* b1W, const void* b1b,
    const void* w2l1W, const void* w2l1b, const void* w2l2W, const void* w2l2b,
    const void* b2l1W, const void* b2l1b, const void* b2l2W, const void* b2l2b) {
  ushort_t* pa = (ushort_t*)(ws + PA_OFF);
  ushort_t* pb = (ushort_t*)(ws + PB_OFF);
  float* cst = (float*)(ws + FB_OFF);
  for (int i = gtid; i < 131072; i += T) {
    int k = i >> 8, n = i & 255;
    pa_store(pa, n, k, f2us(LD<F32>(w1l1W, i)));
    pa_store(pa, 256 + n, k, f2us(LD<F32>(w2l1W, i)));
    pa_store(pa, 512 + n, k, f2us(LD<F32>(w00l1W, i)));
  }
  for (int i = gtid; i < 16384; i += T) {
    int k = i >> 5, n = i & 31;
    pa_store(pa, 768 + n, k, f2us(LD<F32>(b1W, i)));
    pa_store(pa, 800 + n, k, f2us(LD<F32>(b2l1W, i)));
  }
  for (int i = gtid; i < 5120; i += T) {
    int k = i / 10, n = i % 10;
    pa_store(pa, 832 + n, k, f2us(LD<F32>(w01W, i)));
  }
  for (int i = gtid; i < 512; i += T) {
    pa_store(pa, 842, i, f2us(LD<F32>(b00W, i)));
    pa_store(pa, 843, i, f2us(LD<F32>(b01W, i)));
  }
  for (int z = gtid; z < 2048; z += T) {
    int ks = z >> 7, qq = (z >> 5) & 3, lm = 12 + ((z >> 3) & 3), j = z & 7;
    pa[(size_t)52 * 8192 + ks * 512 + (qq * 16 + lm) * 8 + j] = 0;
  }
  for (int i = gtid; i < 139264; i += T) {
    int k = i / 544, n = i % 544;
    pb_store(pb, n, k, f2us(LD<F32>(w1l2W, i)));
  }
  for (int i = gtid; i < 8192; i += T) {
    int k = i >> 5, n = i & 31;
    pb_store(pb, 544 + n, k, f2us(LD<F32>(w2l2W, i)));
  }
  // PB tiles 36/37: w00l2 (256x4) in cols 0..3, zeros elsewhere
  for (int i = gtid; i < 8192; i += T) {
    int k = i & 255, lm = (i >> 8) & 15, tt = 36 + (i >> 12);
    ushort_t v = (lm < 4) ? f2us(LD<F32>(w00l2W, k * 4 + lm)) : (ushort_t)0;
    pb_store(pb, tt * 16 + lm, k, v);
  }
  // consts
  for (int i = gtid; i < NCST; i += T) {
    float x;
    if (i < 896) {
      int c = i;
      if (c < 256) x = LD<F32>(w1l1b, c);
      else if (c < 512) x = LD<F32>(w2l1b, c - 256);
      else if (c < 768) x = LD<F32>(w00l1b, c - 512);
      else if (c < 800) x = LD<F32>(b1b, c - 768);
      else if (c < 832) x = LD<F32>(b2l1b, c - 800);
      else if (c < 842) x = LD<F32>(w01b, c - 832);
      else if (c == 842) x = LD<F32>(b00b, 0);
      else if (c == 843) x = LD<F32>(b01b, 0);
      else x = 0.f;
    } else if (i < 1536) {
      int c = i - 896;
      x = (c < 544) ? LD<F32>(w1l2b, c) : (c < 576 ? LD<F32>(w2l2b, c - 544) : 0.f);
    } else if (i < 1792) {
      int j = i - 1536; float s = 0.f;
      for (int z = 0; z < 16; ++z) s += LD<F32>(w00l1W, (size_t)(512 + z) * 256 + j);
      x = s;
    } else if (i < 2816) x = LD<F32>(w00l2W, i - 1792);
    else if (i < 2820) x = LD<F32>(w00l2b, i - 2816);
    else if (i < 2852) x = LD<F32>(b2l2W, i - 2820);
    else if (i == 2852) x = LD<F32>(b2l2b, 0);
    else { float s = 0.f; for (int z = 0; z < 16; ++z) s += LD<F32>(b00W, 512 + z); x = s; }
    cst[i] = x;
  }
}

__global__ __launch_bounds__(256) void prep_kernel(char* ws, const void* states,
    const void* w00l1W, const void* w00l1b, const void* w00l2W, const void* w00l2b,
    const void* b00W, const void* b00b,
    const void* w01W, const void* w01b, const void* b01W, const void* b01b,
    const void* w1l1W, const void* w1l1b, const void* w1l2W, const void* w1l2b,
    const void* b1W, const void* b1b,
    const void* w2l1W, const void* w2l1b, const void* w2l2W, const void* w2l2b,
    const void* b2l1W, const void* b2l1b, const void* b2l2W, const void* b2l2b) {
  int gtid = blockIdx.x * 256 + threadIdx.x;
  int T = gridDim.x * 256;
  if (detect_f32(states))
    prep_body<true>(gtid, T, ws, w00l1W, w00l1b, w00l2W, w00l2b, b00W, b00b,
        w01W, w01b, b01W, b01b, w1l1W, w1l1b, w1l2W, w1l2b, b1W, b1b,
        w2l1W, w2l1b, w2l2W, w2l2b, b2l1W, b2l1b, b2l2W, b2l2b);
  else
    prep_body<false>(gtid, T, ws, w00l1W, w00l1b, w00l2W, w00l2b, b00W, b00b,
        w01W, w01b, b01W, b01b, w1l1W, w1l1b, w1l2W, w1l2b, b1W, b1b,
        w2l1W, w2l1b, w2l2W, w2l2b, b2l1W, b2l1b, b2l2W, b2l2b);
}

// ---------------- main MFMA kernel: 32 rows/block, 8 waves ----------------
struct SmemM {
  union {
    __align__(16) ushort_t sA[2][8192];   // states, lane order (phase A only)
    __align__(16) ushort_t w1a[32][544];  // |w1 raw| bf16 (phase B output)
  } u;
  __align__(16) ushort_t Am1[2][4096];    // relu(s@w1l1+b), lane order
  __align__(16) ushort_t Am2[2][4096];    // relu(s@w2l1+b), lane order
  __align__(16) ushort_t hbC[2][4096];    // relu(s@w00l1+b), lane order
  __align__(16) ushort_t hbS[2][4096];    // relu(s@w00l1+b+hd), lane order
  float hd[256];
  float b1v[32][32];
  float rbv[32][32];
  float w2v[32][32];
  float w01v[32][12];
  float qv[32][10];
  unsigned char cr[32][64];
  float w0c[32][4], w0s[32][4];
  float gq[32][18];
  float gbv[32], b01v[32];
  float hid[32][33];
};

template <bool F32>
__device__ void mixer_body(SmemM& sm, const char* ws, int n0,
    const void* qvals, const int* crel, const void* states, void* out) {
  const int tid = threadIdx.x;                // 0..511
  const int lane = tid & 63, wv = tid >> 6;   // 8 waves
  const int q = lane >> 4, lm = lane & 15;
  const int b_blk = n0 >> 6;
  const ushort_t* pa = (const ushort_t*)(ws + PA_OFF);
  const ushort_t* pb = (const ushort_t*)(ws + PB_OFF);
  const float* cstg = (const float*)(ws + FB_OFF);

  int sidx[7]; bool sreal[7];
#pragma unroll
  for (int i = 0; i < 7; ++i) {
    int s = wv + 8 * i;
    sreal[i] = (s < 53);
    sidx[i] = sreal[i] ? s : wv;
  }
  const ushort_t* baseA = pa + lane * 8;

  // ---- stage: batched deep loads; issue depth-3 A-phase B-tile ring ----
  short8 bA[3][7];
  if (F32) {
    f32x4 va[8];
#pragma unroll
    for (int it = 0; it < 4; ++it) {
      int fi = tid + it * 512;
      int ln = fi & 63, ks = (fi >> 6) & 15, G = fi >> 10;
      int row = G * 16 + (ln & 15), col = ks * 32 + (ln >> 4) * 8;
      const f32x4* p = (const f32x4*)((const float*)states + (size_t)(n0 + row) * 512 + col);
      va[2 * it] = p[0];
      va[2 * it + 1] = p[1];
    }
#pragma unroll
    for (int d = 0; d < 3; ++d)
#pragma unroll
      for (int i = 0; i < 7; ++i)
        bA[d][i] = *(const short8*)(baseA + (size_t)sidx[i] * 8192 + d * 512);
#pragma unroll
    for (int it = 0; it < 4; ++it) {
      int fi = tid + it * 512;
      int ln = fi & 63, ks = (fi >> 6) & 15, G = fi >> 10;
      f32x4 v0 = va[2 * it], v1 = va[2 * it + 1];
      ushort_t v[8];
      v[0] = f2us(v0[0]); v[1] = f2us(v0[1]); v[2] = f2us(v0[2]); v[3] = f2us(v0[3]);
      v[4] = f2us(v1[0]); v[5] = f2us(v1[1]); v[6] = f2us(v1[2]); v[7] = f2us(v1[3]);
      *(short8*)&sm.u.sA[G][(size_t)(ks * 64 + ln) * 8] = *(short8*)v;
    }
  } else {
    short8 vb[2];
#pragma unroll
    for (int it = 0; it < 2; ++it) {
      int fi = tid + it * 512;
      int ln = fi & 63, ks = (fi >> 6) & 15, G = fi >> 10;
      int row = G * 16 + (ln & 15), col = ks * 32 + (ln >> 4) * 8;
      vb[it] = *(const short8*)((const ushort_t*)states + (size_t)(n0 + row) * 512 + col);
    }
#pragma unroll
    for (int d = 0; d < 3; ++d)
#pragma unroll
      for (int i = 0; i < 7; ++i)
        bA[d][i] = *(const short8*)(baseA + (size_t)sidx[i] * 8192 + d * 512);
#pragma unroll
    for (int it = 0; it < 2; ++it) {
      int fi = tid + it * 512;
      int ln = fi & 63, ks = (fi >> 6) & 15, G = fi >> 10;
      *(short8*)&sm.u.sA[G][(size_t)(ks * 64 + ln) * 8] = vb[it];
    }
  }
  for (int i = tid; i < 320; i += 512) sm.qv[i / 10][i % 10] = LD<F32>(qvals, (size_t)(n0 + i / 10) * 10 + i % 10);
  for (int i = tid; i < 2048; i += 512) sm.cr[i >> 6][i & 63] = (unsigned char)crel[(size_t)n0 * 64 + i];
  if (tid < 256) sm.hd[tid] = cstg[1536 + tid];
  __syncthreads();

  // ---- Phase A: ks-outer, 7 strips/wave, depth-3 prefetch ring ----
  {
    f32x4 accA[7][2];
#pragma unroll
    for (int i = 0; i < 7; ++i) { accA[i][0] = (f32x4){0,0,0,0}; accA[i][1] = (f32x4){0,0,0,0}; }
#pragma unroll
    for (int ks = 0; ks < 16; ++ks) {
      const int d = ks % 3;
      short8 a0 = *(const short8*)&sm.u.sA[0][(ks * 64 + lane) * 8];
      short8 a1 = *(const short8*)&sm.u.sA[1][(ks * 64 + lane) * 8];
#pragma unroll
      for (int i = 0; i < 7; ++i) {
        accA[i][0] = MFMA16(a0, bA[d][i], accA[i][0]);
        accA[i][1] = MFMA16(a1, bA[d][i], accA[i][1]);
      }
      if (ks + 3 < 16) {
#pragma unroll
        for (int i = 0; i < 7; ++i)
          bA[d][i] = *(const short8*)(baseA + (size_t)sidx[i] * 8192 + (ks + 3) * 512);
      }
    }
    // writeback
#pragma unroll
    for (int i = 0; i < 7; ++i) {
      if (!sreal[i]) continue;
      int c = sidx[i] * 16 + lm;
      if (c >= 844) continue;
      float bias = cstg[c];
      int ks2 = (c & 255) >> 5, q2 = (c >> 3) & 3, j2 = c & 7;
      int li = (ks2 * 64 + q2 * 16 + q * 4) * 8 + j2;
#pragma unroll
      for (int G = 0; G < 2; ++G) {
        f32x4 acc = accA[i][G];
        int rb = G * 16 + q * 4;
        if (c < 256) {
#pragma unroll
          for (int g = 0; g < 4; ++g) {
            float v = acc[g] + bias;
            sm.Am1[G][li + g * 8] = f2us(v > 0.f ? v : 0.f);
          }
        } else if (c < 512) {
#pragma unroll
          for (int g = 0; g < 4; ++g) {
            float v = acc[g] + bias;
            sm.Am2[G][li + g * 8] = f2us(v > 0.f ? v : 0.f);
          }
        } else if (c < 768) {
          float hdv = sm.hd[c - 512];
#pragma unroll
          for (int g = 0; g < 4; ++g) {
            float v = acc[g] + bias;
            sm.hbC[G][li + g * 8] = f2us(v > 0.f ? v : 0.f);
            float vs = v + hdv;
            sm.hbS[G][li + g * 8] = f2us(vs > 0.f ? vs : 0.f);
          }
        } else if (c < 800) {
#pragma unroll
          for (int g = 0; g < 4; ++g) sm.b1v[rb + g][c - 768] = acc[g] + bias;
        } else if (c < 832) {
#pragma unroll
          for (int g = 0; g < 4; ++g) { float v = acc[g] + bias; sm.rbv[rb + g][c - 800] = v > 0.f ? v : 0.f; }
        } else if (c < 842) {
#pragma unroll
          for (int g = 0; g < 4; ++g) sm.w01v[rb + g][c - 832] = acc[g] + bias;
        } else if (c == 842) {
#pragma unroll
          for (int g = 0; g < 4; ++g) sm.gbv[rb + g] = acc[g] + bias;
        } else {
#pragma unroll
          for (int g = 0; g < 4; ++g) sm.b01v[rb + g] = acc[g] + bias;
        }
      }
    }
  }

  // phase-B strips + depth-3 ring issued before the barrier
  int tix[5]; bool treal[5];
#pragma unroll
  for (int i = 0; i < 5; ++i) {
    int t = wv + 8 * i;
    treal[i] = (t < 38);
    tix[i] = treal[i] ? t : wv;
  }
  const ushort_t* baseB = pb + lane * 8;
  short8 bB[3][5];
#pragma unroll
  for (int d = 0; d < 3; ++d)
#pragma unroll
    for (int i = 0; i < 5; ++i)
      bB[d][i] = *(const short8*)(baseB + (size_t)tix[i] * 4096 + d * 512);
  __syncthreads();

  // ---- Phase B: 38 tiles, depth-3 ring. A per strip: Am1 / Am2 / hbC / hbS ----
  {
    const ushort_t* As0[5]; const ushort_t* As1[5];
#pragma unroll
    for (int i = 0; i < 5; ++i) {
      int t = tix[i];
      As0[i] = (t < 34) ? sm.Am1[0] : (t < 36 ? sm.Am2[0] : (t == 36 ? sm.hbC[0] : sm.hbS[0]));
      As1[i] = (t < 34) ? sm.Am1[1] : (t < 36 ? sm.Am2[1] : (t == 36 ? sm.hbC[1] : sm.hbS[1]));
    }
    f32x4 accB[5][2];
#pragma unroll
    for (int i = 0; i < 5; ++i) { accB[i][0] = (f32x4){0,0,0,0}; accB[i][1] = (f32x4){0,0,0,0}; }
#pragma unroll
    for (int ks = 0; ks < 8; ++ks) {
      const int d = ks % 3;
      int ao = (ks * 64 + lane) * 8;
#pragma unroll
      for (int i = 0; i < 5; ++i) {
        short8 x0 = *(const short8*)(As0[i] + ao);
        short8 x1 = *(const short8*)(As1[i] + ao);
        accB[i][0] = MFMA16(x0, bB[d][i], accB[i][0]);
        accB[i][1] = MFMA16(x1, bB[d][i], accB[i][1]);
      }
      if (ks + 3 < 8) {
#pragma unroll
        for (int i = 0; i < 5; ++i)
          bB[d][i] = *(const short8*)(baseB + (size_t)tix[i] * 4096 + (ks + 3) * 512);
      }
    }
#pragma unroll
    for (int i = 0; i < 5; ++i) {
      if (!treal[i]) continue;
      int t = tix[i];
      int c = t * 16 + lm;
#pragma unroll
      for (int G = 0; G < 2; ++G) {
        f32x4 acc = accB[i][G];
        int rb = G * 16 + q * 4;
        if (t < 34) {
          float bias = cstg[896 + c];
#pragma unroll
          for (int g = 0; g < 4; ++g) sm.u.w1a[rb + g][c] = f2us(fabsf(acc[g] + bias));
        } else if (t < 36) {
          float bias = cstg[896 + c];
          int e = c - 544;
#pragma unroll
          for (int g = 0; g < 4; ++g) sm.w2v[rb + g][e] = fabsf(acc[g] + bias);
        } else if (t == 36) {
          if (lm < 4) {
            float bias = cstg[2816 + lm];
#pragma unroll
            for (int g = 0; g < 4; ++g) sm.w0c[rb + g][lm] = acc[g] + bias;
          }
        } else {
          if (lm < 4) {
            float bias = cstg[2816 + lm];
#pragma unroll
            for (int g = 0; g < 4; ++g) sm.w0s[rb + g][lm] = acc[g] + bias;
          }
        }
      }
    }
  }
  __syncthreads();

  // ---- C2: gq ----
  {
    int r = tid >> 4, v = tid & 15;
    bool sp = (v == b_blk);
    const float* w0 = sp ? sm.w0s[r] : sm.w0c[r];
    float g = sm.gbv[r] + (sp ? cstg[2853] : 0.f);
#pragma unroll
    for (int k = 0; k < 4; ++k) {
      int a = sm.cr[r][k * 16 + v];
      g = fmaf(sm.qv[r][a], fabsf(w0[k]), g);
    }
    sm.gq[r][v] = g;
  }
  if (tid < 32) {
    float o = sm.b01v[tid];
#pragma unroll
    for (int a = 0; a < 10; ++a) o = fmaf(sm.qv[tid][a], sm.w01v[tid][a], o);
    sm.gq[tid][16] = o;
  }
  __syncthreads();

  // ---- C3: hidden = elu(sum_v gq*|w1| + b1); fuse *w2 + rb*b2l2W ----
  for (int p = tid; p < 1024; p += 512) {
    int r = p >> 5, e = p & 31;
    float h = sm.b1v[r][e];
#pragma unroll
    for (int v = 0; v < 17; ++v) h = fmaf(sm.gq[r][v], us2f(sm.u.w1a[r][v * 32 + e]), h);
    float hid = h > 0.f ? h : (expf(h) - 1.f);
    sm.hid[r][e] = hid * sm.w2v[r][e] + sm.rbv[r][e] * cstg[2820 + e];
  }
  __syncthreads();

  // ---- C4: reduce + store ----
  if (tid < 32) {
    float y = cstg[2852];
#pragma unroll
    for (int e = 0; e < 32; ++e) y += sm.hid[tid][e];
    if (F32) ((float*)out)[n0 + tid] = y;
    else ((bf16*)out)[n0 + tid] = __float2bfloat16(y);
  }
}

__global__ __launch_bounds__(512, 2) void causal_mixer_mfma(const char* ws,
    const void* qvals, const int* crel, const void* states, void* out) {
  __shared__ SmemM sm;
  int n0 = blockIdx.x * 32;
  if (detect_f32(states))
    mixer_body<true>(sm, ws, n0, qvals, crel, states, out);
  else
    mixer_body<false>(sm, ws, n0, qvals, crel, states, out);
}

extern "C" void kernel_launch(void* const* d_in, const int* in_sizes, int n_in,
                              void* d_out, int out_size, void* d_ws, size_t ws_size,
                              hipStream_t stream) {
  char* ws = (char*)d_ws;
  hipLaunchKernelGGL(prep_kernel, dim3(512), dim3(256), 0, stream, ws, d_in[2],
      d_in[3], d_in[4], d_in[5], d_in[6], d_in[7], d_in[8],
      d_in[9], d_in[10], d_in[11], d_in[12],
      d_in[13], d_in[14], d_in[15], d_in[16], d_in[17], d_in[18],
      d_in[19], d_in[20], d_in[21], d_in[22], d_in[23], d_in[24],
      d_in[25], d_in[26]);
  hipLaunchKernelGGL(causal_mixer_mfma, dim3(256), dim3(512), 0, stream, ws,
      d_in[0], (const int*)d_in[1], d_in[2], d_out);
}